// Round 8
// baseline (65.183 us; speedup 1.0000x reference)
//
#include <hip/hip_runtime.h>
#include <math.h>

#define IH 512
#define IW 512
#define NPX (IH*IW)

// column-D kernel geometry
#define BW 64                // tile width = wave width
#define BH 16                // tile height (4 waves x 4 rows)
#define YROWS 30             // rows -7..22
#define YCOLS 78             // cols -7..70
#define YSZ (YROWS*YCOLS)    // 2340
#define RROWS 26             // rows -5..20
#define RCOLS 74             // cols -5..68
#define RCH (RROWS*RCOLS)    // 1924
#define VPITCH 72            // float4 slots per wave (68 used)
#define NSLICE 4

// mono-fallback geometry (round-5 kernel)
#define TS 32
#define YHALO 7
#define RHALO 5
#define YD (TS + 2*YHALO)    // 46
#define RD (TS + 2*RHALO)    // 42
#define RSZ (RD*RD)
#define MYSZ (YD*YD)

#define FSQRT(x) __builtin_amdgcn_sqrtf(x)
#if __has_builtin(__builtin_amdgcn_exp2f)
#define FEXP2(x) __builtin_amdgcn_exp2f(x)
#else
#define FEXP2(x) exp2f(x)
#endif

// Compiler-only fence: cross-LANE deps through wave-private LDS scratch are
// invisible to per-lane alias analysis (round-7 failure: reads reordered
// around the write). Hardware needs nothing -- same-wave DS ops execute in
// order -- but the compiler must not move LDS ops across these points.
#define WAVE_LDS_FENCE() asm volatile("" ::: "memory")

// ---------------- column-D compute kernel: dx-group per blockIdx.z -----------
// wave = 64 distinct columns; per shift each lane computes D at its own column
// (8 sub+fma, rolling Y loads: 1 new ds_read per dy), vertical box via prefix
// -> V[4], ds_write_b128 to wave-private scratch, 4 neighbor V4 reads form the
// 5-col horizontal box. Edge D-columns (-2,-1,64,65) by lanes 0-3 masked.
// No s_barrier in the loop (scratch is wave-private); fences per above.
// NO min-waves clamp (round-2: (256,4) forced VGPR=64 -> 0.5GB spill).
__global__ __launch_bounds__(256)
void nlm_part(const float* __restrict__ rgb,
              const float* __restrict__ sigma,
              float4* __restrict__ ws) {
    __shared__ float YL[YSZ];
    __shared__ float RGBL[3*RCH];
    __shared__ float4 VS[4*VPITCH];

    const int tid   = threadIdx.x;
    const int lane  = tid & 63;
    const int wavei = tid >> 6;
    const int tx0 = blockIdx.x * BW;
    const int ty0 = blockIdx.y * BH;
    const int slice = blockIdx.z;

    const float* Rp = rgb;
    const float* Gp = rgb + NPX;
    const float* Bp = rgb + 2*NPX;

    // stage luminance: rows -7..22, cols -7..70
    for (int idx = tid; idx < YSZ; idx += 256) {
        int a = idx / YCOLS, b = idx - a*YCOLS;
        int gy = (ty0 + a - 7) & (IH-1);
        int gx = (tx0 + b - 7) & (IW-1);
        int g = gy*IW + gx;
        YL[idx] = 0.299f*Rp[g] + 0.587f*Gp[g] + 0.114f*Bp[g];
    }
    // stage RGB: rows -5..20, cols -5..68
    for (int idx = tid; idx < RCH; idx += 256) {
        int a = idx / RCOLS, b = idx - a*RCOLS;
        int gy = (ty0 + a - 5) & (IH-1);
        int gx = (tx0 + b - 5) & (IW-1);
        int g = gy*IW + gx;
        RGBL[idx]       = Rp[g];
        RGBL[RCH+idx]   = Gp[g];
        RGBL[2*RCH+idx] = Bp[g];
    }
    __syncthreads();

    const float m2 = -1.4426950408889634f /
                     (fmaxf(sigma[0]*2.0f, 0.0f) + 1e-6f);

    const int c  = lane;         // output column in tile
    const int r0 = wavei*4;      // strip start row (0,4,8,12)

    // minuend Y cache: rows r0-2..r0+5 at col c (YL row idx = r0+5+i)
    float yb8[8];
    #pragma unroll
    for (int i = 0; i < 8; ++i)
        yb8[i] = YL[(r0+5+i)*YCOLS + (c+7)];

    // edge lanes own ext D-columns -2,-1,64,65 (scratch slots 0,1,66,67)
    const bool ext  = (lane < 4);
    const int  ec    = (lane < 2) ? (lane - 2) : (lane + 62);
    const int  eslot = (lane < 2) ? lane       : (lane + 64);
    float ybe8[8];
    if (ext) {
        #pragma unroll
        for (int i = 0; i < 8; ++i)
            ybe8[i] = YL[(r0+5+i)*YCOLS + (ec+7)];
    }

    float accR[4]={0,0,0,0}, accG[4]={0,0,0,0},
          accB[4]={0,0,0,0}, den[4]={0,0,0,0};

    float4* vbase = VS + wavei*VPITCH;    // wave-private scratch

    const int dxlo  = (slice < 3) ? (-5 + 3*slice) : 4;
    const int dxcnt = (slice < 3) ? 3 : 2;

    for (int u = 0; u < dxcnt; ++u) {
        const int dx = dxlo + u;
        const int ysb   = r0*YCOLS + (c  - dx + 7);   // subtrahend col base
        const int yse   = r0*YCOLS + (ec - dx + 7);   // ext subtrahend base
        const int rgb_b = r0*RCOLS + (c  - dx + 5);

        // rolling subtrahend rows: slot j holds YL row r0+j' (j' = i+k)
        float sub8[8], sube8[8];
        #pragma unroll
        for (int j = 0; j < 8; ++j)
            sub8[j] = YL[ysb + j*YCOLS];
        if (ext) {
            #pragma unroll
            for (int j = 0; j < 8; ++j)
                sube8[j] = YL[yse + j*YCOLS];
        }

        #pragma unroll
        for (int k = 0; k <= 10; ++k) {               // dy = 5 - k
            if (k > 0) {
                sub8[(k+7)&7] = YL[ysb + (k+7)*YCOLS];
                if (ext) sube8[(k+7)&7] = YL[yse + (k+7)*YCOLS];
            }
            // own-column D + vertical box via prefix (square folded into fma)
            float pre[9]; pre[0] = 0.f;
            #pragma unroll
            for (int i = 0; i < 8; ++i) {
                float d = yb8[i] - sub8[(i+k)&7];
                pre[i+1] = fmaf(d, d, pre[i]);
            }
            float4 V = make_float4(pre[5]-pre[0], pre[6]-pre[1],
                                   pre[7]-pre[2], pre[8]-pre[3]);

            WAVE_LDS_FENCE();   // prev-k neighbor reads must precede this write
            vbase[c+2] = V;
            if (ext) {
                float pe[9]; pe[0] = 0.f;
                #pragma unroll
                for (int i = 0; i < 8; ++i) {
                    float d = ybe8[i] - sube8[(i+k)&7];
                    pe[i+1] = fmaf(d, d, pe[i]);
                }
                vbase[eslot] = make_float4(pe[5]-pe[0], pe[6]-pe[1],
                                           pe[7]-pe[2], pe[8]-pe[3]);
            }
            WAVE_LDS_FENCE();   // writes must precede neighbor reads

            // horizontal 5-col box from neighbor V4s (own V from register)
            float4 s0 = vbase[c];
            float4 s1 = vbase[c+1];
            float4 s3 = vbase[c+3];
            float4 s4 = vbase[c+4];
            float bxx[4];
            bxx[0] = s0.x + s1.x + V.x + s3.x + s4.x;
            bxx[1] = s0.y + s1.y + V.y + s3.y + s4.y;
            bxx[2] = s0.z + s1.z + V.z + s3.z + s4.z;
            bxx[3] = s0.w + s1.w + V.w + s3.w + s4.w;
            #pragma unroll
            for (int rr = 0; rr < 4; ++rr) {
                float w = FEXP2(FSQRT(bxx[rr]) * m2);
                const int off = rgb_b + (rr + k)*RCOLS;
                accR[rr] = fmaf(w, RGBL[off],        accR[rr]);
                accG[rr] = fmaf(w, RGBL[RCH+off],    accG[rr]);
                accB[rr] = fmaf(w, RGBL[2*RCH+off],  accB[rr]);
                den[rr] += w;
            }
        }
    }

    #pragma unroll
    for (int rr = 0; rr < 4; ++rr) {
        int px = (ty0 + r0 + rr)*IW + tx0 + c;
        ws[(size_t)slice*NPX + px] =
            make_float4(accR[rr], accG[rr], accB[rr], den[rr]);
    }
}

// ---------------- combine: sum nslice slices, normalize, clip ----------------
__global__ __launch_bounds__(256)
void nlm_combine(const float4* __restrict__ ws, float* __restrict__ out,
                 int nslice) {
    int px = blockIdx.x * 256 + threadIdx.x;
    float r = 0.f, g = 0.f, b = 0.f, w = 0.f;
    for (int s = 0; s < nslice; ++s) {
        float4 v = ws[(size_t)s * NPX + px];
        r += v.x; g += v.y; b += v.z; w += v.w;
    }
    float iw = 1.0f / w;
    out[px]           = fminf(fmaxf(r * iw, 0.f), 1.f);
    out[NPX + px]     = fminf(fmaxf(g * iw, 0.f), 1.f);
    out[2 * NPX + px] = fminf(fmaxf(b * iw, 0.f), 1.f);
}

// ---------------- fallback: round-5 monolithic kernel (ws too small) ---------
__global__ __launch_bounds__(256)
void nlm_mono(const float* __restrict__ rgb,
              const float* __restrict__ sigma,
              float* __restrict__ out) {
    __shared__ float Y[MYSZ];
    __shared__ float RGBL[3 * RSZ];

    const int tid = threadIdx.x;
    const int tx0 = blockIdx.x * TS;
    const int ty0 = blockIdx.y * TS;

    const float* Rp = rgb;
    const float* Gp = rgb + NPX;
    const float* Bp = rgb + 2 * NPX;

    for (int idx = tid; idx < MYSZ; idx += 256) {
        int a = idx / YD, b = idx - a * YD;
        int gy = (ty0 + a - YHALO) & (IH - 1);
        int gx = (tx0 + b - YHALO) & (IW - 1);
        int g = gy * IW + gx;
        Y[idx] = 0.299f * Rp[g] + 0.587f * Gp[g] + 0.114f * Bp[g];
    }
    for (int idx = tid; idx < RSZ; idx += 256) {
        int a = idx / RD, b = idx - a * RD;
        int gy = (ty0 + a - RHALO) & (IH - 1);
        int gx = (tx0 + b - RHALO) & (IW - 1);
        int g = gy * IW + gx;
        RGBL[idx]           = Rp[g];
        RGBL[RSZ + idx]     = Gp[g];
        RGBL[2 * RSZ + idx] = Bp[g];
    }
    __syncthreads();

    const float minv_h = -1.0f / (fmaxf(sigma[0] * 2.0f, 0.0f) + 1e-6f);
    const int tx = tid & 31;
    const int tz = tid >> 5;
    const int r0 = tz * 4;

    const int ybase = (YHALO + r0 - 2) * YD + (YHALO + tx - 2);
    float yb[8][5];
    #pragma unroll
    for (int i = 0; i < 8; ++i)
        #pragma unroll
        for (int b = 0; b < 5; ++b)
            yb[i][b] = Y[ybase + i * YD + b];

    float accR[4] = {0.f,0.f,0.f,0.f}, accG[4] = {0.f,0.f,0.f,0.f};
    float accB[4] = {0.f,0.f,0.f,0.f}, den[4] = {0.f,0.f,0.f,0.f};

    for (int dx = -5; dx <= 5; ++dx) {
        const int ybd = (YHALO + r0 - 7) * YD + (YHALO + tx - 2 - dx);
        const int rbd = (RHALO + r0 - 5) * RD + (RHALO + tx - dx);

        #pragma unroll
        for (int k = 0; k <= 10; ++k) {
            float hs[8];
            #pragma unroll
            for (int i = 0; i < 8; ++i) {
                float s = 0.f;
                #pragma unroll
                for (int b = 0; b < 5; ++b) {
                    float d = yb[i][b] - Y[ybd + (i + k) * YD + b];
                    s = fmaf(d, d, s);
                }
                hs[i] = s;
            }
            float pre[9];
            pre[0] = 0.f;
            #pragma unroll
            for (int i = 0; i < 8; ++i) pre[i + 1] = pre[i] + hs[i];
            #pragma unroll
            for (int rr = 0; rr < 4; ++rr) {
                float box = pre[rr + 5] - pre[rr];
                float w = __expf(FSQRT(box) * minv_h);
                const int s2 = rbd + (rr + k) * RD;
                accR[rr] = fmaf(w, RGBL[s2], accR[rr]);
                accG[rr] = fmaf(w, RGBL[RSZ + s2], accG[rr]);
                accB[rr] = fmaf(w, RGBL[2 * RSZ + s2], accB[rr]);
                den[rr] += w;
            }
        }
    }

    #pragma unroll
    for (int rr = 0; rr < 4; ++rr) {
        int px = (ty0 + r0 + rr) * IW + tx0 + tx;
        float iw = 1.0f / den[rr];
        out[px]           = fminf(fmaxf(accR[rr] * iw, 0.f), 1.f);
        out[NPX + px]     = fminf(fmaxf(accG[rr] * iw, 0.f), 1.f);
        out[2 * NPX + px] = fminf(fmaxf(accB[rr] * iw, 0.f), 1.f);
    }
}

extern "C" void kernel_launch(void* const* d_in, const int* in_sizes, int n_in,
                              void* d_out, int out_size, void* d_ws, size_t ws_size,
                              hipStream_t stream) {
    const float* rgb   = (const float*)d_in[0];
    const float* sigma = (const float*)d_in[1];
    float* out = (float*)d_out;

    const size_t need = (size_t)NSLICE * NPX * sizeof(float4);
    if (ws_size >= need) {
        float4* ws = (float4*)d_ws;
        dim3 grid(IW / BW, IH / BH, NSLICE);   // 8 x 32 x 4 = 1024 blocks
        nlm_part<<<grid, dim3(256), 0, stream>>>(rgb, sigma, ws);
        nlm_combine<<<dim3(NPX / 256), dim3(256), 0, stream>>>(ws, out, NSLICE);
    } else {
        dim3 grid(IW / TS, IH / TS);
        nlm_mono<<<grid, dim3(256), 0, stream>>>(rgb, sigma, out);
    }
}

// Round 9
// 45.792 us; speedup vs baseline: 1.4234x; 1.4234x over previous
//
#include <hip/hip_runtime.h>
#include <math.h>

#define IH 512
#define IW 512
#define NPX (IH*IW)

// column-D + shuffle-box geometry
#define TW 60                // output columns per tile (64 lanes -> D cols -2..61)
#define BH 16                // tile height (4 waves x 4 rows)
#define NXT 9                // ceil(512/60)
#define YROWS 30             // image rows -7..22
#define YCOLS 74             // image cols -7..66
#define YSZ2 (YROWS*YCOLS)   // 2220
#define RROWS 26             // rows -5..20
#define RCOLS 74             // cols -5..68
#define RCH2 (RROWS*RCOLS)   // 1924
#define NSLICE 4

// mono-fallback geometry (round-5 kernel)
#define TS 32
#define YHALO 7
#define RHALO 5
#define YD (TS + 2*YHALO)
#define RD (TS + 2*RHALO)
#define RSZ (RD*RD)
#define MYSZ (YD*YD)

#define FSQRT(x) __builtin_amdgcn_sqrtf(x)
#if __has_builtin(__builtin_amdgcn_exp2f)
#define FEXP2(x) __builtin_amdgcn_exp2f(x)
#else
#define FEXP2(x) exp2f(x)
#endif

// lane shuffle: pull value from lane (addr>>2)&63 -- register-only crossbar,
// no LDS aliasing, no fences needed (round-8 post-mortem: "memory" fences
// around LDS scratch exploded VGPR to 204 and serialized the loop).
__device__ __forceinline__ float shf(float v, int addr) {
    return __int_as_float(__builtin_amdgcn_ds_bpermute(addr, __float_as_int(v)));
}

// ---------------- column-D compute kernel: dx-group per blockIdx.z -----------
// Wave = 64 D-columns (cols -2..61 of a 60-wide output tile). Per shift each
// lane: 1 rolling ds_read (subtrahend Y), 8 sub+8 fma prefix -> V[4] vertical
// box, horizontal 5-col box via 12 ds_bpermute (3-ladder x 4 components),
// 4x sqrt/exp2, 12 RGB LDS reads + 16 fma. Lanes 60-63 compute D only (their
// box/output is garbage and not stored).
// NO min-waves clamp (round-2: (256,4) forced VGPR=64 -> 0.5GB spill).
__global__ __launch_bounds__(256)
void nlm_part(const float* __restrict__ rgb,
              const float* __restrict__ sigma,
              float4* __restrict__ ws) {
    __shared__ float YL[YSZ2];
    __shared__ float RGBL[3*RCH2];

    const int tid   = threadIdx.x;
    const int lane  = tid & 63;
    const int wavei = tid >> 6;
    const int tx0 = blockIdx.x * TW;
    const int ty0 = blockIdx.y * BH;
    const int slice = blockIdx.z;

    const float* Rp = rgb;
    const float* Gp = rgb + NPX;
    const float* Bp = rgb + 2*NPX;

    // stage luminance: rows -7..22, cols -7..66 (circular)
    for (int idx = tid; idx < YSZ2; idx += 256) {
        int a = idx / YCOLS, b = idx - a*YCOLS;
        int gy = (ty0 + a - 7) & (IH-1);
        int gx = (tx0 + b - 7) & (IW-1);
        int g = gy*IW + gx;
        YL[idx] = 0.299f*Rp[g] + 0.587f*Gp[g] + 0.114f*Bp[g];
    }
    // stage RGB: rows -5..20, cols -5..68 (circular)
    for (int idx = tid; idx < RCH2; idx += 256) {
        int a = idx / RCOLS, b = idx - a*RCOLS;
        int gy = (ty0 + a - 5) & (IH-1);
        int gx = (tx0 + b - 5) & (IW-1);
        int g = gy*IW + gx;
        RGBL[idx]        = Rp[g];
        RGBL[RCH2+idx]   = Gp[g];
        RGBL[2*RCH2+idx] = Bp[g];
    }
    __syncthreads();

    const float m2 = -1.4426950408889634f /
                     (fmaxf(sigma[0]*2.0f, 0.0f) + 1e-6f);

    const int l  = lane;         // lane; D col cd = l-2; output col = l (<60)
    const int r0 = wavei*4;      // strip start row

    // shuffle addresses (byte): source lanes l+1, l+2, l+4 (wrap mod 64 ok)
    const int a1 = ((l + 1) & 63) << 2;
    const int a2 = ((l + 2) & 63) << 2;
    const int a4 = ((l + 4) & 63) << 2;

    // minuend Y at D col cd=l-2: rows r0-2..r0+5  (LDS: row r0+5+i, col l+5)
    float yb8[8];
    #pragma unroll
    for (int i = 0; i < 8; ++i)
        yb8[i] = YL[(r0+5+i)*YCOLS + (l+5)];

    float accR[4]={0,0,0,0}, accG[4]={0,0,0,0},
          accB[4]={0,0,0,0}, den[4]={0,0,0,0};

    const int dxlo  = (slice < 3) ? (-5 + 3*slice) : 4;
    const int dxcnt = (slice < 3) ? 3 : 2;

    for (int u = 0; u < dxcnt; ++u) {
        const int dx = dxlo + u;
        const int ysb   = r0*YCOLS + (l + 5 - dx);    // subtrahend col cd-dx
        const int rgb_b = r0*RCOLS + (l + 5 - dx);    // rgb col l-dx

        // rolling subtrahend rows: slot j holds image row r0+j-7 at k=0
        float sub8[8];
        #pragma unroll
        for (int j = 0; j < 8; ++j)
            sub8[j] = YL[ysb + j*YCOLS];

        #pragma unroll
        for (int k = 0; k <= 10; ++k) {               // dy = 5 - k
            if (k > 0)
                sub8[(k+7)&7] = YL[ysb + (7+k)*YCOLS];

            // own-column E + vertical box via prefix (square folded into fma)
            float pre[9]; pre[0] = 0.f;
            #pragma unroll
            for (int i = 0; i < 8; ++i) {
                float d = yb8[i] - sub8[(i+k)&7];
                pre[i+1] = fmaf(d, d, pre[i]);
            }
            float V[4];
            #pragma unroll
            for (int rr = 0; rr < 4; ++rr) V[rr] = pre[rr+5] - pre[rr];

            // horizontal 5-col box: box[l] = sum of V over lanes l..l+4
            // (V at lane j = vertical sum at D col j-2 -> box centered col l)
            float box[4];
            #pragma unroll
            for (int rr = 0; rr < 4; ++rr) {
                float t1 = V[rr] + shf(V[rr], a1);    // lanes l, l+1
                float t2 = t1 + shf(t1, a2);          // lanes l..l+3
                box[rr] = t2 + shf(V[rr], a4);        // + lane l+4
            }
            #pragma unroll
            for (int rr = 0; rr < 4; ++rr) {
                float w = FEXP2(FSQRT(fmaxf(box[rr], 0.f)) * m2);
                const int off = rgb_b + (rr + k)*RCOLS;
                accR[rr] = fmaf(w, RGBL[off],         accR[rr]);
                accG[rr] = fmaf(w, RGBL[RCH2+off],    accG[rr]);
                accB[rr] = fmaf(w, RGBL[2*RCH2+off],  accB[rr]);
                den[rr] += w;
            }
        }
    }

    if (l < TW && tx0 + l < IW) {
        #pragma unroll
        for (int rr = 0; rr < 4; ++rr) {
            int px = (ty0 + r0 + rr)*IW + tx0 + l;
            ws[(size_t)slice*NPX + px] =
                make_float4(accR[rr], accG[rr], accB[rr], den[rr]);
        }
    }
}

// ---------------- combine: sum nslice slices, normalize, clip ----------------
__global__ __launch_bounds__(256)
void nlm_combine(const float4* __restrict__ ws, float* __restrict__ out,
                 int nslice) {
    int px = blockIdx.x * 256 + threadIdx.x;
    float r = 0.f, g = 0.f, b = 0.f, w = 0.f;
    for (int s = 0; s < nslice; ++s) {
        float4 v = ws[(size_t)s * NPX + px];
        r += v.x; g += v.y; b += v.z; w += v.w;
    }
    float iw = 1.0f / w;
    out[px]           = fminf(fmaxf(r * iw, 0.f), 1.f);
    out[NPX + px]     = fminf(fmaxf(g * iw, 0.f), 1.f);
    out[2 * NPX + px] = fminf(fmaxf(b * iw, 0.f), 1.f);
}

// ---------------- fallback: round-5 monolithic kernel (ws too small) ---------
__global__ __launch_bounds__(256)
void nlm_mono(const float* __restrict__ rgb,
              const float* __restrict__ sigma,
              float* __restrict__ out) {
    __shared__ float Y[MYSZ];
    __shared__ float RGBL[3 * RSZ];

    const int tid = threadIdx.x;
    const int tx0 = blockIdx.x * TS;
    const int ty0 = blockIdx.y * TS;

    const float* Rp = rgb;
    const float* Gp = rgb + NPX;
    const float* Bp = rgb + 2 * NPX;

    for (int idx = tid; idx < MYSZ; idx += 256) {
        int a = idx / YD, b = idx - a * YD;
        int gy = (ty0 + a - YHALO) & (IH - 1);
        int gx = (tx0 + b - YHALO) & (IW - 1);
        int g = gy * IW + gx;
        Y[idx] = 0.299f * Rp[g] + 0.587f * Gp[g] + 0.114f * Bp[g];
    }
    for (int idx = tid; idx < RSZ; idx += 256) {
        int a = idx / RD, b = idx - a * RD;
        int gy = (ty0 + a - RHALO) & (IH - 1);
        int gx = (tx0 + b - RHALO) & (IW - 1);
        int g = gy * IW + gx;
        RGBL[idx]           = Rp[g];
        RGBL[RSZ + idx]     = Gp[g];
        RGBL[2 * RSZ + idx] = Bp[g];
    }
    __syncthreads();

    const float minv_h = -1.0f / (fmaxf(sigma[0] * 2.0f, 0.0f) + 1e-6f);
    const int tx = tid & 31;
    const int tz = tid >> 5;
    const int r0 = tz * 4;

    const int ybase = (YHALO + r0 - 2) * YD + (YHALO + tx - 2);
    float yb[8][5];
    #pragma unroll
    for (int i = 0; i < 8; ++i)
        #pragma unroll
        for (int b = 0; b < 5; ++b)
            yb[i][b] = Y[ybase + i * YD + b];

    float accR[4] = {0.f,0.f,0.f,0.f}, accG[4] = {0.f,0.f,0.f,0.f};
    float accB[4] = {0.f,0.f,0.f,0.f}, den[4] = {0.f,0.f,0.f,0.f};

    for (int dx = -5; dx <= 5; ++dx) {
        const int ybd = (YHALO + r0 - 7) * YD + (YHALO + tx - 2 - dx);
        const int rbd = (RHALO + r0 - 5) * RD + (RHALO + tx - dx);

        #pragma unroll
        for (int k = 0; k <= 10; ++k) {
            float hs[8];
            #pragma unroll
            for (int i = 0; i < 8; ++i) {
                float s = 0.f;
                #pragma unroll
                for (int b = 0; b < 5; ++b) {
                    float d = yb[i][b] - Y[ybd + (i + k) * YD + b];
                    s = fmaf(d, d, s);
                }
                hs[i] = s;
            }
            float pre[9];
            pre[0] = 0.f;
            #pragma unroll
            for (int i = 0; i < 8; ++i) pre[i + 1] = pre[i] + hs[i];
            #pragma unroll
            for (int rr = 0; rr < 4; ++rr) {
                float box = pre[rr + 5] - pre[rr];
                float w = __expf(FSQRT(box) * minv_h);
                const int s2 = rbd + (rr + k) * RD;
                accR[rr] = fmaf(w, RGBL[s2], accR[rr]);
                accG[rr] = fmaf(w, RGBL[RSZ + s2], accG[rr]);
                accB[rr] = fmaf(w, RGBL[2 * RSZ + s2], accB[rr]);
                den[rr] += w;
            }
        }
    }

    #pragma unroll
    for (int rr = 0; rr < 4; ++rr) {
        int px = (ty0 + r0 + rr) * IW + tx0 + tx;
        float iw = 1.0f / den[rr];
        out[px]           = fminf(fmaxf(accR[rr] * iw, 0.f), 1.f);
        out[NPX + px]     = fminf(fmaxf(accG[rr] * iw, 0.f), 1.f);
        out[2 * NPX + px] = fminf(fmaxf(accB[rr] * iw, 0.f), 1.f);
    }
}

extern "C" void kernel_launch(void* const* d_in, const int* in_sizes, int n_in,
                              void* d_out, int out_size, void* d_ws, size_t ws_size,
                              hipStream_t stream) {
    const float* rgb   = (const float*)d_in[0];
    const float* sigma = (const float*)d_in[1];
    float* out = (float*)d_out;

    const size_t need = (size_t)NSLICE * NPX * sizeof(float4);
    if (ws_size >= need) {
        float4* ws = (float4*)d_ws;
        dim3 grid(NXT, IH / BH, NSLICE);   // 9 x 32 x 4 = 1152 blocks
        nlm_part<<<grid, dim3(256), 0, stream>>>(rgb, sigma, ws);
        nlm_combine<<<dim3(NPX / 256), dim3(256), 0, stream>>>(ws, out, NSLICE);
    } else {
        dim3 grid(IW / TS, IH / TS);
        nlm_mono<<<grid, dim3(256), 0, stream>>>(rgb, sigma, out);
    }
}